// Round 4
// baseline (12394.430 us; speedup 1.0000x reference)
//
#include <hip/hip_runtime.h>
#include <math.h>

// Problem dims
#define T_LEN 128
#define B_SZ  64
#define AD    32
#define ZD    64
#define KMIX  16
#define HID   128

// ---------------- workspace layout ----------------
// bf16 weights (ushort), packed [K/2][512][2] per matrix:
//   W0IH ushort ofs 0      (16384)
//   W0HH ushort ofs 16384  (65536)
//   W1IH ushort ofs 81920  (65536)
//   W1HH ushort ofs 147456 (65536)
// float region (offsets in floats):
#define WS_B0 106496
#define WS_B1 107008
#define WS_Q  107520
#define WS_R  111616
#define WS_W  112640
// total floats: 243712 (~975 KB)

// ---------------- output layout (floats) ----------------
#define OUT_MEANS   0
#define OUT_COVS    524288
#define OUT_NMEANS  34078720
#define OUT_NCOVS   34603008
#define OUT_MATA    68157440
#define OUT_MATC    101711872

__device__ __forceinline__ float sigmoidf_(float x){ return 1.0f/(1.0f + expf(-x)); }

__device__ __forceinline__ unsigned short f2bf(float f){
  unsigned u = __float_as_uint(f);
  u += 0x7FFFu + ((u >> 16) & 1u);
  return (unsigned short)(u >> 16);
}

// ============ prep ============
__global__ __launch_bounds__(256) void prep_kernel(
    const float* __restrict__ Wih0, const float* __restrict__ Whh0,
    const float* __restrict__ bih0, const float* __restrict__ bhh0,
    const float* __restrict__ Wih1, const float* __restrict__ Whh1,
    const float* __restrict__ bih1, const float* __restrict__ bhh1,
    const float* __restrict__ QL,   const float* __restrict__ RL,
    float* __restrict__ ws)
{
  int idx = blockIdx.x*256 + threadIdx.x;
  unsigned short* w16 = (unsigned short*)ws;
  if (idx < 212992) {
    const float* src; int local, base, IN;
    if (idx < 16384)       { src = Wih0; local = idx;          base = 0;      IN = 32; }
    else if (idx < 81920)  { src = Whh0; local = idx - 16384;  base = 16384;  IN = 128; }
    else if (idx < 147456) { src = Wih1; local = idx - 81920;  base = 81920;  IN = 128; }
    else                   { src = Whh1; local = idx - 147456; base = 147456; IN = 128; }
    int pair = local >> 10, g = (local >> 1) & 511, lo = local & 1;
    int k = pair*2 + lo;
    w16[base + local] = f2bf(src[g*IN + k]);
  } else if (idx < 213504) {
    int g = idx - 212992; ws[WS_B0 + g] = bih0[g] + bhh0[g];
  } else if (idx < 214016) {
    int g = idx - 213504; ws[WS_B1 + g] = bih1[g] + bhh1[g];
  } else if (idx < 218112) {              // Q = QL QL^T + 1e-3 I
    int e = idx - 214016; int i = e >> 6, j = e & 63;
    float s = (i==j) ? 1e-3f : 0.f;
    for (int k = 0; k < 64; ++k) s += QL[i*64+k]*QL[j*64+k];
    ws[WS_Q + e] = s;
  } else if (idx < 219136) {              // R = RL RL^T + 1e-3 I
    int e = idx - 218112; int i = e >> 5, j = e & 31;
    float s = (i==j) ? 1e-3f : 0.f;
    for (int k = 0; k < 32; ++k) s += RL[i*32+k]*RL[j*32+k];
    ws[WS_R + e] = s;
  }
}

// ============ 2-layer LSTM + softmax head -> w[T][B][16] ============
__global__ __launch_bounds__(512) void lstm_kernel(
    const float* __restrict__ as_, const float* __restrict__ ws,
    const float* __restrict__ linW, const float* __restrict__ linb,
    float* __restrict__ wout)
{
  const int b = blockIdx.x, tid = threadIdx.x;
  const unsigned* W0ih = (const unsigned*)ws;        // [16][512]
  const unsigned* W0hh = W0ih + 16*512;              // [64][512]
  const unsigned* W1ih = W0hh + 64*512;              // [64][512]
  const unsigned* W1hh = W1ih + 64*512;              // [64][512]

  __shared__ float xs[32];
  __shared__ float h0[128];
  __shared__ float h1[128];
  __shared__ float gbuf[512];
  __shared__ float lg[16];

  float c0 = 0.f, c1 = 0.f;
  if (tid < 128) { h0[tid] = 0.f; h1[tid] = 0.f; }
  const float bias0 = ws[WS_B0 + tid];
  const float bias1 = ws[WS_B1 + tid];
  __syncthreads();

  for (int t = 0; t < T_LEN; ++t) {
    if (tid < 32) xs[tid] = as_[(t*B_SZ + b)*AD + tid];
    __syncthreads();
    { // layer 0
      float acc = bias0;
      #pragma unroll 4
      for (int kk = 0; kk < 16; ++kk) {
        const unsigned u = W0ih[kk*512 + tid];
        acc += __uint_as_float(u << 16) * xs[2*kk]
             + __uint_as_float(u & 0xFFFF0000u) * xs[2*kk+1];
      }
      #pragma unroll 8
      for (int kk = 0; kk < 64; ++kk) {
        const unsigned u = W0hh[kk*512 + tid];
        acc += __uint_as_float(u << 16) * h0[2*kk]
             + __uint_as_float(u & 0xFFFF0000u) * h0[2*kk+1];
      }
      gbuf[tid] = acc;
    }
    __syncthreads();
    if (tid < 128) {
      float ig = sigmoidf_(gbuf[tid]);
      float fg = sigmoidf_(gbuf[tid+128]);
      float gg = tanhf(gbuf[tid+256]);
      float og = sigmoidf_(gbuf[tid+384]);
      c0 = fg*c0 + ig*gg;
      h0[tid] = og * tanhf(c0);
    }
    __syncthreads();
    { // layer 1
      float acc = bias1;
      #pragma unroll 8
      for (int kk = 0; kk < 64; ++kk) {
        const unsigned u = W1ih[kk*512 + tid];
        acc += __uint_as_float(u << 16) * h0[2*kk]
             + __uint_as_float(u & 0xFFFF0000u) * h0[2*kk+1];
      }
      #pragma unroll 8
      for (int kk = 0; kk < 64; ++kk) {
        const unsigned u = W1hh[kk*512 + tid];
        acc += __uint_as_float(u << 16) * h1[2*kk]
             + __uint_as_float(u & 0xFFFF0000u) * h1[2*kk+1];
      }
      gbuf[tid] = acc;
    }
    __syncthreads();
    if (tid < 128) {
      float ig = sigmoidf_(gbuf[tid]);
      float fg = sigmoidf_(gbuf[tid+128]);
      float gg = tanhf(gbuf[tid+256]);
      float og = sigmoidf_(gbuf[tid+384]);
      c1 = fg*c1 + ig*gg;
      h1[tid] = og * tanhf(c1);
    }
    __syncthreads();
    if (tid < 16) {
      float acc = linb[tid];
      #pragma unroll 8
      for (int k = 0; k < 128; ++k) acc += linW[tid*128 + k] * h1[k];
      lg[tid] = acc;
    }
    __syncthreads();
    if (tid == 0) {
      float m = lg[0];
      #pragma unroll
      for (int k = 1; k < 16; ++k) m = fmaxf(m, lg[k]);
      float e[16]; float s = 0.f;
      #pragma unroll
      for (int k = 0; k < 16; ++k) { e[k] = expf(lg[k] - m); s += e[k]; }
      float inv = 1.f / s;
      #pragma unroll
      for (int k = 0; k < 16; ++k) wout[(t*B_SZ + b)*KMIX + k] = e[k]*inv;
    }
    __syncthreads();
  }
}

// ============ mix ============
__global__ __launch_bounds__(256) void mix_kernel(
    const float* __restrict__ w, const float* __restrict__ AK,
    const float* __restrict__ CK, float* __restrict__ out)
{
  float* matA = out + OUT_MATA;
  float* matC = out + OUT_MATC;
  const int tb0 = blockIdx.x * 16;
  const int tid = threadIdx.x;
  __shared__ float wl[16][16];
  { int lt = tid >> 4, k = tid & 15; wl[lt][k] = w[(tb0 + lt)*16 + k]; }
  __syncthreads();

  for (int e = tid; e < ZD*ZD; e += 256) {
    float v[16];
    #pragma unroll
    for (int u = 0; u < 16; ++u) v[u] = 0.f;
    #pragma unroll 4
    for (int k = 0; k < 16; ++k) {
      float a = AK[k*ZD*ZD + e];
      #pragma unroll
      for (int u = 0; u < 16; ++u) v[u] += wl[u][k] * a;
    }
    #pragma unroll
    for (int u = 0; u < 16; ++u) matA[(size_t)(tb0+u)*(ZD*ZD) + e] = v[u];
  }
  for (int e = tid; e < AD*ZD; e += 256) {
    float v[16];
    #pragma unroll
    for (int u = 0; u < 16; ++u) v[u] = 0.f;
    #pragma unroll 4
    for (int k = 0; k < 16; ++k) {
      float a = CK[k*AD*ZD + e];
      #pragma unroll
      for (int u = 0; u < 16; ++u) v[u] += wl[u][k] * a;
    }
    #pragma unroll
    for (int u = 0; u < 16; ++u) matC[(size_t)(tb0+u)*(AD*ZD) + e] = v[u];
  }
}

// ============ Kalman filter: one block (1024 thr) per batch ============
// Augmented-column trick: col 64 of covp carries meanp; mean flows through
// the same matmuls. W-form update: cov_t = covp - W^T W, W = L^{-1}[CP| Cmeanp-a].
__global__ __launch_bounds__(1024) void kalman_kernel(
    const float* __restrict__ as_, const float* __restrict__ ws,
    float* __restrict__ out)
{
  const int b = blockIdx.x, tid = threadIdx.x;
  const float* Rm = ws + WS_R;
  const float* Qg = ws + WS_Q;
  const float* matA = out + OUT_MATA;
  const float* matC = out + OUT_MATC;
  float* means  = out + OUT_MEANS;
  float* covs   = out + OUT_COVS;
  float* nmeans = out + OUT_NMEANS;
  float* ncovs  = out + OUT_NCOVS;

  __shared__ __align__(16) float covp[64*68];   // aug: col 64 = meanp
  __shared__ __align__(16) float At[2][64*68];  // A^T, double-buffered
  __shared__ float Cm[2][32*65];                // C, stride 65
  __shared__ __align__(16) float CPm[32*68];    // [CP | Cmeanp - a]
  __shared__ __align__(16) float Wm[32*68];     // L^{-1} CPaug
  __shared__ float Smat[32*36];
  __shared__ __align__(16) float tmpm[64*68];   // A @ covt_aug
  __shared__ __align__(16) float Ql[64*68];     // Q staged

  // ---- init: covp = [I | 0], stage Q
  for (int e = tid; e < 64*64; e += 1024) {
    const int i = e >> 6, j = e & 63;
    Ql[i*68 + j]   = Qg[e];
    covp[i*68 + j] = (i == j) ? 1.f : 0.f;
  }
  if (tid < 64) covp[tid*68 + 64] = 0.f;

  // ---- prefetch ownership
  const bool isA1 = (tid >= 128);
  const int  qa1  = tid - 128;            // float4 chunk 0..895
  const bool isA2 = (tid >= 128 && tid < 256);
  const int  qa2  = tid - 128 + 896;      // chunks 896..1023
  const bool isC  = (tid >= 256 && tid < 768);
  const int  qc   = tid - 256;            // C float4 chunk 0..511
  float4 pa1 = make_float4(0,0,0,0), pa2 = pa1, pc = pa1;

  { // load + stage t=0 into buf 0
    const float* Ag = matA + (size_t)b*4096;
    const float* Cg = matC + (size_t)b*2048;
    if (isA1) pa1 = *(const float4*)&Ag[qa1*4];
    if (isA2) pa2 = *(const float4*)&Ag[qa2*4];
    if (isC)  pc  = *(const float4*)&Cg[qc*4];
    if (isA1) { const int i = qa1>>4, j = (qa1&15)*4;
      At[0][(j+0)*68+i]=pa1.x; At[0][(j+1)*68+i]=pa1.y; At[0][(j+2)*68+i]=pa1.z; At[0][(j+3)*68+i]=pa1.w; }
    if (isA2) { const int i = qa2>>4, j = (qa2&15)*4;
      At[0][(j+0)*68+i]=pa2.x; At[0][(j+1)*68+i]=pa2.y; At[0][(j+2)*68+i]=pa2.z; At[0][(j+3)*68+i]=pa2.w; }
    if (isC)  { const int i = qc>>4, c0 = (qc&15)*4;
      Cm[0][i*65+c0]=pc.x; Cm[0][i*65+c0+1]=pc.y; Cm[0][i*65+c0+2]=pc.z; Cm[0][i*65+c0+3]=pc.w; }
  }
  __syncthreads();

  int cur = 0;
  for (int t = 0; t < T_LEN; ++t) {
    const int tb = t*B_SZ + b;
    const int nxt = cur ^ 1;
    // issue prefetch for t+1 (lands during P1..P2; LDS-written in P3)
    if (t < T_LEN-1) {
      const float* Ag = matA + (size_t)(tb+64)*4096;
      const float* Cg = matC + (size_t)(tb+64)*2048;
      if (isA1) pa1 = *(const float4*)&Ag[qa1*4];
      if (isA2) pa2 = *(const float4*)&Ag[qa2*4];
      if (isC)  pc  = *(const float4*)&Cg[qc*4];
    }
    float areg = 0.f;
    if ((tid & 31) == 31) areg = as_[(size_t)tb*AD + (tid>>5)];

    // ---- P1: CPaug = C @ covp_aug   (32 x 65)
    {
      const int i = tid >> 5, j0 = (tid & 31)*2;
      const bool do64 = ((tid & 31) == 31);
      const float* Crow = &Cm[cur][i*65];
      float ax = 0.f, ay = 0.f, s64 = 0.f;
      #pragma unroll 8
      for (int k = 0; k < 64; ++k) {
        const float a = Crow[k];
        const float2 b2 = *(const float2*)&covp[k*68 + j0];
        ax += a*b2.x; ay += a*b2.y;
        if (do64) s64 += a * covp[k*68 + 64];
      }
      CPm[i*68 + j0]   = ax;
      CPm[i*68 + j0+1] = ay;
      if (do64) CPm[i*68 + 64] = s64 - areg;   // C meanp - a  (= -innov)
    }
    __syncthreads();
    // ---- P2: S = CP @ C^T + R   (32 x 32)
    {
      const int i = tid >> 5, j = tid & 31;
      const float* CProw = &CPm[i*68];
      const float* Crow  = &Cm[cur][j*65];
      float s = Rm[i*32 + j];
      #pragma unroll 8
      for (int k = 0; k < 64; ++k) s += CProw[k] * Crow[k];
      Smat[i*36 + j] = s;
    }
    __syncthreads();
    // ---- P3: waves 0-1 Cholesky (redundant) + forward solve; waves 2-15 stage t+1
    {
      const int wv = tid >> 6, lane = tid & 63;
      if (wv < 2) {
        float Lr[32];
        float invd = 0.f;   // lane k ends up holding 1/L[k][k]; ONLY static
                            // indexing into Lr (Lr[lane] was the round-3
                            // scratch-spill bug: runtime index -> local mem,
                            // 3 GB of scratch traffic per dispatch)
        if (lane < 32) {
          #pragma unroll
          for (int j = 0; j < 32; ++j) Lr[j] = Smat[lane*36 + j];
          #pragma unroll
          for (int k = 0; k < 32; ++k) {
            const float piv = __shfl(Lr[k], k);
            const float ir  = 1.0f / sqrtf(piv);
            const float lik = Lr[k] * ir;
            invd = (lane == k) ? ir : invd;     // static select, no array idx
            #pragma unroll
            for (int j = k+1; j < 32; ++j) {
              const float ljk = __shfl(lik, j);
              Lr[j] -= lik * ljk;
            }
            Lr[k] = lik;
          }
        }
        // column-oriented forward solve via shfl-broadcast of L.
        // ALL 64 lanes of both waves stay ACTIVE through the shfl chain
        // (shfl from an inactive source lane is undefined — round-2 bug).
        // Wave 1 computes col 64 redundantly in every lane; lane 0 writes.
        const int c = (wv == 0) ? lane : 64;
        {
          float s[32];
          #pragma unroll
          for (int i = 0; i < 32; ++i) s[i] = CPm[i*68 + c];
          #pragma unroll
          for (int k = 0; k < 32; ++k) {
            const float dk = __shfl(invd, k);
            const float y  = s[k] * dk;
            if (wv == 0 || lane == 0) Wm[k*68 + c] = y;
            #pragma unroll
            for (int i = k+1; i < 32; ++i) {
              const float lik = __shfl(Lr[k], i);
              s[i] -= lik * y;
            }
          }
        }
      } else if (t < T_LEN-1) {
        if (isA1) { const int i = qa1>>4, j = (qa1&15)*4;
          At[nxt][(j+0)*68+i]=pa1.x; At[nxt][(j+1)*68+i]=pa1.y; At[nxt][(j+2)*68+i]=pa1.z; At[nxt][(j+3)*68+i]=pa1.w; }
        if (isA2) { const int i = qa2>>4, j = (qa2&15)*4;
          At[nxt][(j+0)*68+i]=pa2.x; At[nxt][(j+1)*68+i]=pa2.y; At[nxt][(j+2)*68+i]=pa2.z; At[nxt][(j+3)*68+i]=pa2.w; }
        if (isC)  { const int i = qc>>4, c0 = (qc&15)*4;
          Cm[nxt][i*65+c0]=pc.x; Cm[nxt][i*65+c0+1]=pc.y; Cm[nxt][i*65+c0+2]=pc.z; Cm[nxt][i*65+c0+3]=pc.w; }
      }
    }
    __syncthreads();
    // ---- P5: covt_aug = covp_aug - W^T W (in place); write covs, means
    {
      const int j = tid >> 4, c0 = (tid & 15)*4;
      const bool do64 = ((tid & 15) == 15);
      float4 acc = make_float4(0,0,0,0); float s64 = 0.f;
      #pragma unroll 4
      for (int k = 0; k < 32; ++k) {
        const float a = Wm[k*68 + j];
        const float4 b4 = *(const float4*)&Wm[k*68 + c0];
        acc.x += a*b4.x; acc.y += a*b4.y; acc.z += a*b4.z; acc.w += a*b4.w;
        if (do64) s64 += a * Wm[k*68 + 64];
      }
      float4 cv = *(const float4*)&covp[j*68 + c0];
      cv.x -= acc.x; cv.y -= acc.y; cv.z -= acc.z; cv.w -= acc.w;
      *(float4*)&covp[j*68 + c0] = cv;
      *(float4*)&covs[(size_t)tb*4096 + j*64 + c0] = cv;
      if (do64) {
        const float mt = covp[j*68 + 64] - s64;   // mean_t
        covp[j*68 + 64] = mt;
        means[(size_t)tb*64 + j] = mt;
      }
    }
    __syncthreads();
    // ---- P6: tmpm = A @ covt_aug ; col64 = mean_next
    {
      const int i = tid >> 4, c0 = (tid & 15)*4;
      const bool do64 = ((tid & 15) == 15);
      const float* Atb = At[cur];
      float4 acc = make_float4(0,0,0,0); float s64 = 0.f;
      #pragma unroll 4
      for (int k = 0; k < 64; ++k) {
        const float a = Atb[k*68 + i];
        const float4 b4 = *(const float4*)&covp[k*68 + c0];
        acc.x += a*b4.x; acc.y += a*b4.y; acc.z += a*b4.z; acc.w += a*b4.w;
        if (do64) s64 += a * covp[k*68 + 64];
      }
      *(float4*)&tmpm[i*68 + c0] = acc;
      if (do64) {
        tmpm[i*68 + 64] = s64;
        nmeans[(size_t)tb*64 + i] = s64;
      }
    }
    __syncthreads();
    // ---- P7: covnext = tmpm @ A^T + Q -> covp ; carry mean_next
    {
      const int i = tid >> 4, j0 = (tid & 15)*4;
      const float* Atb  = At[cur];
      const float* trow = &tmpm[i*68];
      float4 acc = make_float4(0,0,0,0);
      #pragma unroll 4
      for (int k = 0; k < 64; ++k) {
        const float a = trow[k];
        const float4 b4 = *(const float4*)&Atb[k*68 + j0];
        acc.x += a*b4.x; acc.y += a*b4.y; acc.z += a*b4.z; acc.w += a*b4.w;
      }
      const float4 qv = *(const float4*)&Ql[i*68 + j0];
      acc.x += qv.x; acc.y += qv.y; acc.z += qv.z; acc.w += qv.w;
      *(float4*)&covp[i*68 + j0] = acc;
      if ((tid & 15) == 15) covp[i*68 + 64] = tmpm[i*68 + 64];
    }
    __syncthreads();
    // ---- P8: symmetrize (average) + write ncovs
    float4 m4;
    {
      const int i = tid >> 4, j0 = (tid & 15)*4;
      const float4 own = *(const float4*)&covp[i*68 + j0];
      m4.x = 0.5f*(own.x + covp[(j0+0)*68 + i]);
      m4.y = 0.5f*(own.y + covp[(j0+1)*68 + i]);
      m4.z = 0.5f*(own.z + covp[(j0+2)*68 + i]);
      m4.w = 0.5f*(own.w + covp[(j0+3)*68 + i]);
    }
    __syncthreads();
    {
      const int i = tid >> 4, j0 = (tid & 15)*4;
      *(float4*)&covp[i*68 + j0] = m4;
      *(float4*)&ncovs[(size_t)tb*4096 + i*64 + j0] = m4;
    }
    __syncthreads();
    cur = nxt;
  }
}

extern "C" void kernel_launch(void* const* d_in, const int* in_sizes, int n_in,
                              void* d_out, int out_size, void* d_ws, size_t ws_size,
                              hipStream_t stream) {
  const float* as_  = (const float*)d_in[0];
  const float* AK   = (const float*)d_in[1];
  const float* CK   = (const float*)d_in[2];
  const float* QL   = (const float*)d_in[3];
  const float* RL   = (const float*)d_in[4];
  const float* linW = (const float*)d_in[5];
  const float* linb = (const float*)d_in[6];
  const float* Wih0 = (const float*)d_in[7];
  const float* Whh0 = (const float*)d_in[8];
  const float* bih0 = (const float*)d_in[9];
  const float* bhh0 = (const float*)d_in[10];
  const float* Wih1 = (const float*)d_in[11];
  const float* Whh1 = (const float*)d_in[12];
  const float* bih1 = (const float*)d_in[13];
  const float* bhh1 = (const float*)d_in[14];
  float* out = (float*)d_out;
  float* ws  = (float*)d_ws;

  prep_kernel<<<856, 256, 0, stream>>>(Wih0, Whh0, bih0, bhh0,
                                       Wih1, Whh1, bih1, bhh1, QL, RL, ws);
  lstm_kernel<<<B_SZ, 512, 0, stream>>>(as_, ws, linW, linb, ws + WS_W);
  mix_kernel<<<(T_LEN*B_SZ)/16, 256, 0, stream>>>(ws + WS_W, AK, CK, out);
  kalman_kernel<<<B_SZ, 1024, 0, stream>>>(as_, ws, out);
}

// Round 5
// 7975.527 us; speedup vs baseline: 1.5541x; 1.5541x over previous
//
#include <hip/hip_runtime.h>
#include <math.h>

// Problem dims
#define T_LEN 128
#define B_SZ  64
#define AD    32
#define ZD    64
#define KMIX  16
#define HID   128

// ---------------- workspace layout ----------------
// bf16 weights (ushort), packed [K/2][512][2] per matrix:
//   W0IH ushort ofs 0      (16384)
//   W0HH ushort ofs 16384  (65536)
//   W1IH ushort ofs 81920  (65536)
//   W1HH ushort ofs 147456 (65536)
// float region (offsets in floats):
#define WS_B0 106496
#define WS_B1 107008
#define WS_Q  107520
#define WS_R  111616
#define WS_W  112640

// ---------------- output layout (floats) ----------------
#define OUT_MEANS   0
#define OUT_COVS    524288
#define OUT_NMEANS  34078720
#define OUT_NCOVS   34603008
#define OUT_MATA    68157440
#define OUT_MATC    101711872

__device__ __forceinline__ float sigmoidf_(float x){ return 1.0f/(1.0f + expf(-x)); }

__device__ __forceinline__ unsigned short f2bf(float f){
  unsigned u = __float_as_uint(f);
  u += 0x7FFFu + ((u >> 16) & 1u);
  return (unsigned short)(u >> 16);
}

// ============ prep ============
__global__ __launch_bounds__(256) void prep_kernel(
    const float* __restrict__ Wih0, const float* __restrict__ Whh0,
    const float* __restrict__ bih0, const float* __restrict__ bhh0,
    const float* __restrict__ Wih1, const float* __restrict__ Whh1,
    const float* __restrict__ bih1, const float* __restrict__ bhh1,
    const float* __restrict__ QL,   const float* __restrict__ RL,
    float* __restrict__ ws)
{
  int idx = blockIdx.x*256 + threadIdx.x;
  unsigned short* w16 = (unsigned short*)ws;
  if (idx < 212992) {
    const float* src; int local, base, IN;
    if (idx < 16384)       { src = Wih0; local = idx;          base = 0;      IN = 32; }
    else if (idx < 81920)  { src = Whh0; local = idx - 16384;  base = 16384;  IN = 128; }
    else if (idx < 147456) { src = Wih1; local = idx - 81920;  base = 81920;  IN = 128; }
    else                   { src = Whh1; local = idx - 147456; base = 147456; IN = 128; }
    int pair = local >> 10, g = (local >> 1) & 511, lo = local & 1;
    int k = pair*2 + lo;
    w16[base + local] = f2bf(src[g*IN + k]);
  } else if (idx < 213504) {
    int g = idx - 212992; ws[WS_B0 + g] = bih0[g] + bhh0[g];
  } else if (idx < 214016) {
    int g = idx - 213504; ws[WS_B1 + g] = bih1[g] + bhh1[g];
  } else if (idx < 218112) {              // Q = QL QL^T + 1e-3 I
    int e = idx - 214016; int i = e >> 6, j = e & 63;
    float s = (i==j) ? 1e-3f : 0.f;
    for (int k = 0; k < 64; ++k) s += QL[i*64+k]*QL[j*64+k];
    ws[WS_Q + e] = s;
  } else if (idx < 219136) {              // R = RL RL^T + 1e-3 I
    int e = idx - 218112; int i = e >> 5, j = e & 31;
    float s = (i==j) ? 1e-3f : 0.f;
    for (int k = 0; k < 32; ++k) s += RL[i*32+k]*RL[j*32+k];
    ws[WS_R + e] = s;
  }
}

// ============ 2-layer LSTM + softmax head -> w[T][B][16] ============
__global__ __launch_bounds__(512) void lstm_kernel(
    const float* __restrict__ as_, const float* __restrict__ ws,
    const float* __restrict__ linW, const float* __restrict__ linb,
    float* __restrict__ wout)
{
  const int b = blockIdx.x, tid = threadIdx.x;
  const unsigned* W0ih = (const unsigned*)ws;        // [16][512]
  const unsigned* W0hh = W0ih + 16*512;              // [64][512]
  const unsigned* W1ih = W0hh + 64*512;              // [64][512]
  const unsigned* W1hh = W1ih + 64*512;              // [64][512]

  __shared__ float xs[32];
  __shared__ float h0[128];
  __shared__ float h1[128];
  __shared__ float gbuf[512];
  __shared__ float lg[16];

  float c0 = 0.f, c1 = 0.f;
  if (tid < 128) { h0[tid] = 0.f; h1[tid] = 0.f; }
  const float bias0 = ws[WS_B0 + tid];
  const float bias1 = ws[WS_B1 + tid];
  __syncthreads();

  for (int t = 0; t < T_LEN; ++t) {
    if (tid < 32) xs[tid] = as_[(t*B_SZ + b)*AD + tid];
    __syncthreads();
    { // layer 0
      float acc = bias0;
      #pragma unroll 4
      for (int kk = 0; kk < 16; ++kk) {
        const unsigned u = W0ih[kk*512 + tid];
        acc += __uint_as_float(u << 16) * xs[2*kk]
             + __uint_as_float(u & 0xFFFF0000u) * xs[2*kk+1];
      }
      #pragma unroll 8
      for (int kk = 0; kk < 64; ++kk) {
        const unsigned u = W0hh[kk*512 + tid];
        acc += __uint_as_float(u << 16) * h0[2*kk]
             + __uint_as_float(u & 0xFFFF0000u) * h0[2*kk+1];
      }
      gbuf[tid] = acc;
    }
    __syncthreads();
    if (tid < 128) {
      float ig = sigmoidf_(gbuf[tid]);
      float fg = sigmoidf_(gbuf[tid+128]);
      float gg = tanhf(gbuf[tid+256]);
      float og = sigmoidf_(gbuf[tid+384]);
      c0 = fg*c0 + ig*gg;
      h0[tid] = og * tanhf(c0);
    }
    __syncthreads();
    { // layer 1
      float acc = bias1;
      #pragma unroll 8
      for (int kk = 0; kk < 64; ++kk) {
        const unsigned u = W1ih[kk*512 + tid];
        acc += __uint_as_float(u << 16) * h0[2*kk]
             + __uint_as_float(u & 0xFFFF0000u) * h0[2*kk+1];
      }
      #pragma unroll 8
      for (int kk = 0; kk < 64; ++kk) {
        const unsigned u = W1hh[kk*512 + tid];
        acc += __uint_as_float(u << 16) * h1[2*kk]
             + __uint_as_float(u & 0xFFFF0000u) * h1[2*kk+1];
      }
      gbuf[tid] = acc;
    }
    __syncthreads();
    if (tid < 128) {
      float ig = sigmoidf_(gbuf[tid]);
      float fg = sigmoidf_(gbuf[tid+128]);
      float gg = tanhf(gbuf[tid+256]);
      float og = sigmoidf_(gbuf[tid+384]);
      c1 = fg*c1 + ig*gg;
      h1[tid] = og * tanhf(c1);
    }
    __syncthreads();
    if (tid < 16) {
      float acc = linb[tid];
      #pragma unroll 8
      for (int k = 0; k < 128; ++k) acc += linW[tid*128 + k] * h1[k];
      lg[tid] = acc;
    }
    __syncthreads();
    if (tid == 0) {
      float m = lg[0];
      #pragma unroll
      for (int k = 1; k < 16; ++k) m = fmaxf(m, lg[k]);
      float e[16]; float s = 0.f;
      #pragma unroll
      for (int k = 0; k < 16; ++k) { e[k] = expf(lg[k] - m); s += e[k]; }
      float inv = 1.f / s;
      #pragma unroll
      for (int k = 0; k < 16; ++k) wout[(t*B_SZ + b)*KMIX + k] = e[k]*inv;
    }
    __syncthreads();
  }
}

// ============ mix ============
__global__ __launch_bounds__(256) void mix_kernel(
    const float* __restrict__ w, const float* __restrict__ AK,
    const float* __restrict__ CK, float* __restrict__ out)
{
  float* matA = out + OUT_MATA;
  float* matC = out + OUT_MATC;
  const int tb0 = blockIdx.x * 16;
  const int tid = threadIdx.x;
  __shared__ float wl[16][16];
  { int lt = tid >> 4, k = tid & 15; wl[lt][k] = w[(tb0 + lt)*16 + k]; }
  __syncthreads();

  for (int e = tid; e < ZD*ZD; e += 256) {
    float v[16];
    #pragma unroll
    for (int u = 0; u < 16; ++u) v[u] = 0.f;
    #pragma unroll 4
    for (int k = 0; k < 16; ++k) {
      float a = AK[k*ZD*ZD + e];
      #pragma unroll
      for (int u = 0; u < 16; ++u) v[u] += wl[u][k] * a;
    }
    #pragma unroll
    for (int u = 0; u < 16; ++u) matA[(size_t)(tb0+u)*(ZD*ZD) + e] = v[u];
  }
  for (int e = tid; e < AD*ZD; e += 256) {
    float v[16];
    #pragma unroll
    for (int u = 0; u < 16; ++u) v[u] = 0.f;
    #pragma unroll 4
    for (int k = 0; k < 16; ++k) {
      float a = CK[k*AD*ZD + e];
      #pragma unroll
      for (int u = 0; u < 16; ++u) v[u] += wl[u][k] * a;
    }
    #pragma unroll
    for (int u = 0; u < 16; ++u) matC[(size_t)(tb0+u)*(AD*ZD) + e] = v[u];
  }
}

// ============ Kalman filter: one block (512 thr, 8 waves) per batch ============
// 512 threads NOT 1024: a 1024-thr block caps the allocator at 64 VGPR/thread
// (observed r3/r4) which spills Lr[32]/s[32] to scratch (3 GB/dispatch).
// (512,2) => 1 block/CU, cap 256 VGPR: arrays stay in registers.
__global__ __launch_bounds__(512, 2) void kalman_kernel(
    const float* __restrict__ as_, const float* __restrict__ ws,
    float* __restrict__ out)
{
  const int b = blockIdx.x, tid = threadIdx.x;
  const float* Rm = ws + WS_R;
  const float* Qg = ws + WS_Q;
  const float* matA = out + OUT_MATA;
  const float* matC = out + OUT_MATC;
  float* means  = out + OUT_MEANS;
  float* covs   = out + OUT_COVS;
  float* nmeans = out + OUT_NMEANS;
  float* ncovs  = out + OUT_NCOVS;

  __shared__ __align__(16) float covp[64*68];   // aug: col 64 = meanp
  __shared__ __align__(16) float At[2][64*68];  // A^T, double-buffered
  __shared__ float Cm[2][32*65];                // C, stride 65
  __shared__ __align__(16) float CPm[32*68];    // [CP | Cmeanp - a]
  __shared__ __align__(16) float Wm[32*68];     // L^{-1} CPaug
  __shared__ float Smat[32*36];
  __shared__ __align__(16) float tmpm[64*68];   // A @ covt_aug
  __shared__ __align__(16) float Ql[64*68];     // Q staged

  // ---- init: covp = [I | 0], stage Q, stage t=0 A/C
  for (int e = tid; e < 64*64; e += 512) {
    const int i = e >> 6, j = e & 63;
    Ql[i*68 + j]   = Qg[e];
    covp[i*68 + j] = (i == j) ? 1.f : 0.f;
  }
  if (tid < 64) covp[tid*68 + 64] = 0.f;
  {
    const float* Ag = matA + (size_t)b*4096;
    const float* Cg = matC + (size_t)b*2048;
    for (int e = tid; e < 4096; e += 512) At[0][(e & 63)*68 + (e >> 6)] = Ag[e];
    for (int e = tid; e < 2048; e += 512) Cm[0][(e >> 6)*65 + (e & 63)] = Cg[e];
  }
  __syncthreads();

  const int su = tid - 128;         // staging thread index 0..383 (waves 2..7)
  float4 pf0, pf1, pf2, pf3;        // named regs -> static indexing (rule #20)

  int cur = 0;
  for (int t = 0; t < T_LEN; ++t) {
    const int tb = t*B_SZ + b;
    const int nxt = cur ^ 1;
    // issue prefetch for t+1 (consumed in P3 by waves 2..7)
    if (t < T_LEN-1 && tid >= 128) {
      const float* Ag = matA + (size_t)(tb+64)*4096;
      const float* Cg = matC + (size_t)(tb+64)*2048;
      { const int c = su;        pf0 = *(const float4*)&Ag[c*4]; }            // 0..383 all A
      { const int c = su + 384;  pf1 = *(const float4*)&Ag[c*4]; }            // 384..767 all A
      { const int c = su + 768;  pf2 = (c < 1024) ? *(const float4*)&Ag[c*4]
                                                  : *(const float4*)&Cg[(c-1024)*4]; }
      { const int c = su + 1152; pf3 = *(const float4*)&Cg[(c-1024)*4]; }     // all C
    }
    float areg = 0.f;
    if ((tid & 15) == 15) areg = as_[(size_t)tb*AD + (tid >> 4)];

    // ---- P1: CPaug = C @ covp_aug   (32 rows x 65)
    {
      const int i = tid >> 4, j0 = (tid & 15)*4;
      const bool do64 = ((tid & 15) == 15);
      const float* Crow = &Cm[cur][i*65];
      float4 acc = make_float4(0,0,0,0); float s64 = 0.f;
      #pragma unroll 8
      for (int k = 0; k < 64; ++k) {
        const float a = Crow[k];
        const float4 b4 = *(const float4*)&covp[k*68 + j0];
        acc.x += a*b4.x; acc.y += a*b4.y; acc.z += a*b4.z; acc.w += a*b4.w;
        if (do64) s64 += a * covp[k*68 + 64];
      }
      *(float4*)&CPm[i*68 + j0] = acc;
      if (do64) CPm[i*68 + 64] = s64 - areg;   // C meanp - a  (= -innov)
    }
    __syncthreads();
    // ---- P2: S = CP @ C^T + R   (32x32, 2 outputs/thread)
    {
      const int i = tid >> 4, j0 = (tid & 15)*2;
      const float* CProw = &CPm[i*68];
      const float* Cr0 = &Cm[cur][(j0+0)*65];
      const float* Cr1 = &Cm[cur][(j0+1)*65];
      float a0 = 0.f, a1 = 0.f;
      #pragma unroll 8
      for (int k = 0; k < 64; ++k) {
        const float cp = CProw[k];
        a0 += cp * Cr0[k];
        a1 += cp * Cr1[k];
      }
      Smat[i*36 + j0+0] = a0 + Rm[i*32 + j0+0];
      Smat[i*36 + j0+1] = a1 + Rm[i*32 + j0+1];
    }
    __syncthreads();
    // ---- P3: waves 0-1 Cholesky + solve; waves 2-7 stage t+1
    {
      const int wv = tid >> 6, lane = tid & 63;
      if (wv < 2) {
        float Lr[32];
        float invd = 0.f;   // lane k holds 1/L[k][k]; static select only
        if (lane < 32) {
          #pragma unroll
          for (int j = 0; j < 32; ++j) Lr[j] = Smat[lane*36 + j];
          #pragma unroll
          for (int k = 0; k < 32; ++k) {
            const float piv = __shfl(Lr[k], k);
            const float ir  = 1.0f / sqrtf(piv);
            const float lik = Lr[k] * ir;
            invd = (lane == k) ? ir : invd;
            #pragma unroll
            for (int j = k+1; j < 32; ++j) {
              const float ljk = __shfl(lik, j);
              Lr[j] -= lik * ljk;
            }
            Lr[k] = lik;
          }
        }
        // column-oriented forward solve; ALL 64 lanes stay active through
        // the shfl chain (shfl from inactive lane undefined — r2 bug).
        const int c = (wv == 0) ? lane : 64;
        {
          float s[32];
          #pragma unroll
          for (int i = 0; i < 32; ++i) s[i] = CPm[i*68 + c];
          #pragma unroll
          for (int k = 0; k < 32; ++k) {
            const float dk = __shfl(invd, k);
            const float y  = s[k] * dk;
            if (wv == 0 || lane == 0) Wm[k*68 + c] = y;
            #pragma unroll
            for (int i = k+1; i < 32; ++i) {
              const float lik = __shfl(Lr[k], i);
              s[i] -= lik * y;
            }
          }
        }
      } else if (t < T_LEN-1) {
        // stage t+1: A chunks 0..1023, C chunks 0..511 (float4 granularity)
        { const int c = su;        const int i = c>>4, j = (c&15)*4;
          At[nxt][(j+0)*68+i]=pf0.x; At[nxt][(j+1)*68+i]=pf0.y; At[nxt][(j+2)*68+i]=pf0.z; At[nxt][(j+3)*68+i]=pf0.w; }
        { const int c = su + 384;  const int i = c>>4, j = (c&15)*4;
          At[nxt][(j+0)*68+i]=pf1.x; At[nxt][(j+1)*68+i]=pf1.y; At[nxt][(j+2)*68+i]=pf1.z; At[nxt][(j+3)*68+i]=pf1.w; }
        { const int c = su + 768;
          if (c < 1024) { const int i = c>>4, j = (c&15)*4;
            At[nxt][(j+0)*68+i]=pf2.x; At[nxt][(j+1)*68+i]=pf2.y; At[nxt][(j+2)*68+i]=pf2.z; At[nxt][(j+3)*68+i]=pf2.w; }
          else { const int cc = c-1024; const int i = cc>>4, c0 = (cc&15)*4;
            Cm[nxt][i*65+c0]=pf2.x; Cm[nxt][i*65+c0+1]=pf2.y; Cm[nxt][i*65+c0+2]=pf2.z; Cm[nxt][i*65+c0+3]=pf2.w; } }
        { const int cc = su + 128; const int i = cc>>4, c0 = (cc&15)*4;
          Cm[nxt][i*65+c0]=pf3.x; Cm[nxt][i*65+c0+1]=pf3.y; Cm[nxt][i*65+c0+2]=pf3.z; Cm[nxt][i*65+c0+3]=pf3.w; }
      }
    }
    __syncthreads();
    // ---- P5: covt_aug = covp_aug - W^T W (in place); write covs, means
    {
      const int j = tid >> 3, c0 = (tid & 7)*8;
      const bool do64 = ((tid & 7) == 7);
      float4 a0 = make_float4(0,0,0,0), a1 = a0; float s64 = 0.f;
      #pragma unroll 4
      for (int k = 0; k < 32; ++k) {
        const float a = Wm[k*68 + j];
        const float4 b0 = *(const float4*)&Wm[k*68 + c0];
        const float4 b1 = *(const float4*)&Wm[k*68 + c0 + 4];
        a0.x += a*b0.x; a0.y += a*b0.y; a0.z += a*b0.z; a0.w += a*b0.w;
        a1.x += a*b1.x; a1.y += a*b1.y; a1.z += a*b1.z; a1.w += a*b1.w;
        if (do64) s64 += a * Wm[k*68 + 64];
      }
      float4 c4a = *(const float4*)&covp[j*68 + c0];
      float4 c4b = *(const float4*)&covp[j*68 + c0 + 4];
      c4a.x -= a0.x; c4a.y -= a0.y; c4a.z -= a0.z; c4a.w -= a0.w;
      c4b.x -= a1.x; c4b.y -= a1.y; c4b.z -= a1.z; c4b.w -= a1.w;
      *(float4*)&covp[j*68 + c0]     = c4a;
      *(float4*)&covp[j*68 + c0 + 4] = c4b;
      *(float4*)&covs[(size_t)tb*4096 + j*64 + c0]     = c4a;
      *(float4*)&covs[(size_t)tb*4096 + j*64 + c0 + 4] = c4b;
      if (do64) {
        const float mt = covp[j*68 + 64] - s64;   // mean_t
        covp[j*68 + 64] = mt;
        means[(size_t)tb*64 + j] = mt;
      }
    }
    __syncthreads();
    // ---- P6: tmpm = A @ covt_aug ; col64 = mean_next
    {
      const int i = tid >> 3, c0 = (tid & 7)*8;
      const bool do64 = ((tid & 7) == 7);
      const float* Atb = At[cur];
      float4 a0 = make_float4(0,0,0,0), a1 = a0; float s64 = 0.f;
      #pragma unroll 4
      for (int k = 0; k < 64; ++k) {
        const float a = Atb[k*68 + i];
        const float4 b0 = *(const float4*)&covp[k*68 + c0];
        const float4 b1 = *(const float4*)&covp[k*68 + c0 + 4];
        a0.x += a*b0.x; a0.y += a*b0.y; a0.z += a*b0.z; a0.w += a*b0.w;
        a1.x += a*b1.x; a1.y += a*b1.y; a1.z += a*b1.z; a1.w += a*b1.w;
        if (do64) s64 += a * covp[k*68 + 64];
      }
      *(float4*)&tmpm[i*68 + c0]     = a0;
      *(float4*)&tmpm[i*68 + c0 + 4] = a1;
      if (do64) {
        tmpm[i*68 + 64] = s64;
        nmeans[(size_t)tb*64 + i] = s64;
      }
    }
    __syncthreads();
    // ---- P7: covnext = tmpm @ A^T + Q -> covp ; carry mean_next
    {
      const int i = tid >> 3, j0 = (tid & 7)*8;
      const float* Atb  = At[cur];
      const float* trow = &tmpm[i*68];
      float4 a0 = make_float4(0,0,0,0), a1 = a0;
      #pragma unroll 4
      for (int k = 0; k < 64; ++k) {
        const float a = trow[k];
        const float4 b0 = *(const float4*)&Atb[k*68 + j0];
        const float4 b1 = *(const float4*)&Atb[k*68 + j0 + 4];
        a0.x += a*b0.x; a0.y += a*b0.y; a0.z += a*b0.z; a0.w += a*b0.w;
        a1.x += a*b1.x; a1.y += a*b1.y; a1.z += a*b1.z; a1.w += a*b1.w;
      }
      const float4 q0 = *(const float4*)&Ql[i*68 + j0];
      const float4 q1 = *(const float4*)&Ql[i*68 + j0 + 4];
      a0.x += q0.x; a0.y += q0.y; a0.z += q0.z; a0.w += q0.w;
      a1.x += q1.x; a1.y += q1.y; a1.z += q1.z; a1.w += q1.w;
      *(float4*)&covp[i*68 + j0]     = a0;
      *(float4*)&covp[i*68 + j0 + 4] = a1;
      if ((tid & 7) == 7) covp[i*68 + 64] = tmpm[i*68 + 64];
    }
    __syncthreads();
    // ---- P8: symmetrize (average) + write ncovs
    float4 m0, m1;
    {
      const int i = tid >> 3, j0 = (tid & 7)*8;
      const float4 o0 = *(const float4*)&covp[i*68 + j0];
      const float4 o1 = *(const float4*)&covp[i*68 + j0 + 4];
      m0.x = 0.5f*(o0.x + covp[(j0+0)*68 + i]);
      m0.y = 0.5f*(o0.y + covp[(j0+1)*68 + i]);
      m0.z = 0.5f*(o0.z + covp[(j0+2)*68 + i]);
      m0.w = 0.5f*(o0.w + covp[(j0+3)*68 + i]);
      m1.x = 0.5f*(o1.x + covp[(j0+4)*68 + i]);
      m1.y = 0.5f*(o1.y + covp[(j0+5)*68 + i]);
      m1.z = 0.5f*(o1.z + covp[(j0+6)*68 + i]);
      m1.w = 0.5f*(o1.w + covp[(j0+7)*68 + i]);
    }
    __syncthreads();
    {
      const int i = tid >> 3, j0 = (tid & 7)*8;
      *(float4*)&covp[i*68 + j0]     = m0;
      *(float4*)&covp[i*68 + j0 + 4] = m1;
      *(float4*)&ncovs[(size_t)tb*4096 + i*64 + j0]     = m0;
      *(float4*)&ncovs[(size_t)tb*4096 + i*64 + j0 + 4] = m1;
    }
    __syncthreads();
    cur = nxt;
  }
}

extern "C" void kernel_launch(void* const* d_in, const int* in_sizes, int n_in,
                              void* d_out, int out_size, void* d_ws, size_t ws_size,
                              hipStream_t stream) {
  const float* as_  = (const float*)d_in[0];
  const float* AK   = (const float*)d_in[1];
  const float* CK   = (const float*)d_in[2];
  const float* QL   = (const float*)d_in[3];
  const float* RL   = (const float*)d_in[4];
  const float* linW = (const float*)d_in[5];
  const float* linb = (const float*)d_in[6];
  const float* Wih0 = (const float*)d_in[7];
  const float* Whh0 = (const float*)d_in[8];
  const float* bih0 = (const float*)d_in[9];
  const float* bhh0 = (const float*)d_in[10];
  const float* Wih1 = (const float*)d_in[11];
  const float* Whh1 = (const float*)d_in[12];
  const float* bih1 = (const float*)d_in[13];
  const float* bhh1 = (const float*)d_in[14];
  float* out = (float*)d_out;
  float* ws  = (float*)d_ws;

  prep_kernel<<<856, 256, 0, stream>>>(Wih0, Whh0, bih0, bhh0,
                                       Wih1, Whh1, bih1, bhh1, QL, RL, ws);
  lstm_kernel<<<B_SZ, 512, 0, stream>>>(as_, ws, linW, linb, ws + WS_W);
  mix_kernel<<<(T_LEN*B_SZ)/16, 256, 0, stream>>>(ws + WS_W, AK, CK, out);
  kalman_kernel<<<B_SZ, 512, 0, stream>>>(as_, ws, out);
}

// Round 6
// 7944.051 us; speedup vs baseline: 1.5602x; 1.0040x over previous
//
#include <hip/hip_runtime.h>
#include <math.h>

// Problem dims
#define T_LEN 128
#define B_SZ  64
#define AD    32
#define ZD    64
#define KMIX  16
#define HID   128

// ---------------- workspace layout ----------------
// bf16 weights (ushort), packed [K/2][512][2] per matrix:
//   W0IH ushort ofs 0      (16384)
//   W0HH ushort ofs 16384  (65536)
//   W1IH ushort ofs 81920  (65536)
//   W1HH ushort ofs 147456 (65536)
// float region (offsets in floats):
#define WS_B0 106496
#define WS_B1 107008
#define WS_Q  107520
#define WS_R  111616
#define WS_W  112640

// ---------------- output layout (floats) ----------------
#define OUT_MEANS   0
#define OUT_COVS    524288
#define OUT_NMEANS  34078720
#define OUT_NCOVS   34603008
#define OUT_MATA    68157440
#define OUT_MATC    101711872

__device__ __forceinline__ float sigmoidf_(float x){ return 1.0f/(1.0f + expf(-x)); }

__device__ __forceinline__ unsigned short f2bf(float f){
  unsigned u = __float_as_uint(f);
  u += 0x7FFFu + ((u >> 16) & 1u);
  return (unsigned short)(u >> 16);
}

// ============ prep ============
__global__ __launch_bounds__(256) void prep_kernel(
    const float* __restrict__ Wih0, const float* __restrict__ Whh0,
    const float* __restrict__ bih0, const float* __restrict__ bhh0,
    const float* __restrict__ Wih1, const float* __restrict__ Whh1,
    const float* __restrict__ bih1, const float* __restrict__ bhh1,
    const float* __restrict__ QL,   const float* __restrict__ RL,
    float* __restrict__ ws)
{
  int idx = blockIdx.x*256 + threadIdx.x;
  unsigned short* w16 = (unsigned short*)ws;
  if (idx < 212992) {
    const float* src; int local, base, IN;
    if (idx < 16384)       { src = Wih0; local = idx;          base = 0;      IN = 32; }
    else if (idx < 81920)  { src = Whh0; local = idx - 16384;  base = 16384;  IN = 128; }
    else if (idx < 147456) { src = Wih1; local = idx - 81920;  base = 81920;  IN = 128; }
    else                   { src = Whh1; local = idx - 147456; base = 147456; IN = 128; }
    int pair = local >> 10, g = (local >> 1) & 511, lo = local & 1;
    int k = pair*2 + lo;
    w16[base + local] = f2bf(src[g*IN + k]);
  } else if (idx < 213504) {
    int g = idx - 212992; ws[WS_B0 + g] = bih0[g] + bhh0[g];
  } else if (idx < 214016) {
    int g = idx - 213504; ws[WS_B1 + g] = bih1[g] + bhh1[g];
  } else if (idx < 218112) {              // Q = QL QL^T + 1e-3 I
    int e = idx - 214016; int i = e >> 6, j = e & 63;
    float s = (i==j) ? 1e-3f : 0.f;
    for (int k = 0; k < 64; ++k) s += QL[i*64+k]*QL[j*64+k];
    ws[WS_Q + e] = s;
  } else if (idx < 219136) {              // R = RL RL^T + 1e-3 I
    int e = idx - 218112; int i = e >> 5, j = e & 31;
    float s = (i==j) ? 1e-3f : 0.f;
    for (int k = 0; k < 32; ++k) s += RL[i*32+k]*RL[j*32+k];
    ws[WS_R + e] = s;
  }
}

// ============ 2-layer LSTM + softmax head -> w[T][B][16] ============
__global__ __launch_bounds__(512) void lstm_kernel(
    const float* __restrict__ as_, const float* __restrict__ ws,
    const float* __restrict__ linW, const float* __restrict__ linb,
    float* __restrict__ wout)
{
  const int b = blockIdx.x, tid = threadIdx.x;
  const unsigned* W0ih = (const unsigned*)ws;        // [16][512]
  const unsigned* W0hh = W0ih + 16*512;              // [64][512]
  const unsigned* W1ih = W0hh + 64*512;              // [64][512]
  const unsigned* W1hh = W1ih + 64*512;              // [64][512]

  __shared__ float xs[32];
  __shared__ float h0[128];
  __shared__ float h1[128];
  __shared__ float gbuf[512];
  __shared__ float lg[16];

  float c0 = 0.f, c1 = 0.f;
  if (tid < 128) { h0[tid] = 0.f; h1[tid] = 0.f; }
  const float bias0 = ws[WS_B0 + tid];
  const float bias1 = ws[WS_B1 + tid];
  __syncthreads();

  for (int t = 0; t < T_LEN; ++t) {
    if (tid < 32) xs[tid] = as_[(t*B_SZ + b)*AD + tid];
    __syncthreads();
    { // layer 0
      float acc = bias0;
      #pragma unroll 4
      for (int kk = 0; kk < 16; ++kk) {
        const unsigned u = W0ih[kk*512 + tid];
        acc += __uint_as_float(u << 16) * xs[2*kk]
             + __uint_as_float(u & 0xFFFF0000u) * xs[2*kk+1];
      }
      #pragma unroll 8
      for (int kk = 0; kk < 64; ++kk) {
        const unsigned u = W0hh[kk*512 + tid];
        acc += __uint_as_float(u << 16) * h0[2*kk]
             + __uint_as_float(u & 0xFFFF0000u) * h0[2*kk+1];
      }
      gbuf[tid] = acc;
    }
    __syncthreads();
    if (tid < 128) {
      float ig = sigmoidf_(gbuf[tid]);
      float fg = sigmoidf_(gbuf[tid+128]);
      float gg = tanhf(gbuf[tid+256]);
      float og = sigmoidf_(gbuf[tid+384]);
      c0 = fg*c0 + ig*gg;
      h0[tid] = og * tanhf(c0);
    }
    __syncthreads();
    { // layer 1
      float acc = bias1;
      #pragma unroll 8
      for (int kk = 0; kk < 64; ++kk) {
        const unsigned u = W1ih[kk*512 + tid];
        acc += __uint_as_float(u << 16) * h0[2*kk]
             + __uint_as_float(u & 0xFFFF0000u) * h0[2*kk+1];
      }
      #pragma unroll 8
      for (int kk = 0; kk < 64; ++kk) {
        const unsigned u = W1hh[kk*512 + tid];
        acc += __uint_as_float(u << 16) * h1[2*kk]
             + __uint_as_float(u & 0xFFFF0000u) * h1[2*kk+1];
      }
      gbuf[tid] = acc;
    }
    __syncthreads();
    if (tid < 128) {
      float ig = sigmoidf_(gbuf[tid]);
      float fg = sigmoidf_(gbuf[tid+128]);
      float gg = tanhf(gbuf[tid+256]);
      float og = sigmoidf_(gbuf[tid+384]);
      c1 = fg*c1 + ig*gg;
      h1[tid] = og * tanhf(c1);
    }
    __syncthreads();
    if (tid < 16) {
      float acc = linb[tid];
      #pragma unroll 8
      for (int k = 0; k < 128; ++k) acc += linW[tid*128 + k] * h1[k];
      lg[tid] = acc;
    }
    __syncthreads();
    if (tid == 0) {
      float m = lg[0];
      #pragma unroll
      for (int k = 1; k < 16; ++k) m = fmaxf(m, lg[k]);
      float e[16]; float s = 0.f;
      #pragma unroll
      for (int k = 0; k < 16; ++k) { e[k] = expf(lg[k] - m); s += e[k]; }
      float inv = 1.f / s;
      #pragma unroll
      for (int k = 0; k < 16; ++k) wout[(t*B_SZ + b)*KMIX + k] = e[k]*inv;
    }
    __syncthreads();
  }
}

// ============ mix ============
__global__ __launch_bounds__(256) void mix_kernel(
    const float* __restrict__ w, const float* __restrict__ AK,
    const float* __restrict__ CK, float* __restrict__ out)
{
  float* matA = out + OUT_MATA;
  float* matC = out + OUT_MATC;
  const int tb0 = blockIdx.x * 16;
  const int tid = threadIdx.x;
  __shared__ float wl[16][16];
  { int lt = tid >> 4, k = tid & 15; wl[lt][k] = w[(tb0 + lt)*16 + k]; }
  __syncthreads();

  for (int e = tid; e < ZD*ZD; e += 256) {
    float v[16];
    #pragma unroll
    for (int u = 0; u < 16; ++u) v[u] = 0.f;
    #pragma unroll 4
    for (int k = 0; k < 16; ++k) {
      float a = AK[k*ZD*ZD + e];
      #pragma unroll
      for (int u = 0; u < 16; ++u) v[u] += wl[u][k] * a;
    }
    #pragma unroll
    for (int u = 0; u < 16; ++u) matA[(size_t)(tb0+u)*(ZD*ZD) + e] = v[u];
  }
  for (int e = tid; e < AD*ZD; e += 256) {
    float v[16];
    #pragma unroll
    for (int u = 0; u < 16; ++u) v[u] = 0.f;
    #pragma unroll 4
    for (int k = 0; k < 16; ++k) {
      float a = CK[k*AD*ZD + e];
      #pragma unroll
      for (int u = 0; u < 16; ++u) v[u] += wl[u][k] * a;
    }
    #pragma unroll
    for (int u = 0; u < 16; ++u) matC[(size_t)(tb0+u)*(AD*ZD) + e] = v[u];
  }
}

// ============ Kalman filter: one block (512 thr, 8 waves) per batch ============
// __launch_bounds__(512, 1): empirically (512,2) gave a 128-VGPR cap (hipcc
// treats arg2 CUDA-style: 2 blocks/CU -> 4 waves/SIMD -> 512/4 = 128) which
// spilled Lr[32]/s[32] -> 1.4 GB of scratch writebacks per dispatch (r5).
// LDS is 123 KB so only 1 block/CU ever fits; (512,1) -> 256-VGPR cap.
__global__ __launch_bounds__(512, 1) void kalman_kernel(
    const float* __restrict__ as_, const float* __restrict__ ws,
    float* __restrict__ out)
{
  const int b = blockIdx.x, tid = threadIdx.x;
  const float* Rm = ws + WS_R;
  const float* Qg = ws + WS_Q;
  const float* matA = out + OUT_MATA;
  const float* matC = out + OUT_MATC;
  float* means  = out + OUT_MEANS;
  float* covs   = out + OUT_COVS;
  float* nmeans = out + OUT_NMEANS;
  float* ncovs  = out + OUT_NCOVS;

  __shared__ __align__(16) float covp[64*68];   // aug: col 64 = meanp
  __shared__ __align__(16) float At[2][64*68];  // A^T, double-buffered
  __shared__ float Cm[2][32*65];                // C, stride 65
  __shared__ __align__(16) float CPm[32*68];    // [CP | Cmeanp - a]
  __shared__ __align__(16) float Wm[32*68];     // L^{-1} CPaug
  __shared__ float Smat[32*36];
  __shared__ __align__(16) float tmpm[64*68];   // A @ covt_aug
  __shared__ __align__(16) float Ql[64*68];     // Q staged

  // ---- init: covp = [I | 0], stage Q, stage t=0 A/C
  for (int e = tid; e < 64*64; e += 512) {
    const int i = e >> 6, j = e & 63;
    Ql[i*68 + j]   = Qg[e];
    covp[i*68 + j] = (i == j) ? 1.f : 0.f;
  }
  if (tid < 64) covp[tid*68 + 64] = 0.f;
  {
    const float* Ag = matA + (size_t)b*4096;
    const float* Cg = matC + (size_t)b*2048;
    for (int e = tid; e < 4096; e += 512) At[0][(e & 63)*68 + (e >> 6)] = Ag[e];
    for (int e = tid; e < 2048; e += 512) Cm[0][(e >> 6)*65 + (e & 63)] = Cg[e];
  }
  __syncthreads();

  const int su = tid - 128;         // staging thread index 0..383 (waves 2..7)
  float4 pf0, pf1, pf2, pf3;        // named regs -> static indexing (rule #20)

  int cur = 0;
  for (int t = 0; t < T_LEN; ++t) {
    const int tb = t*B_SZ + b;
    const int nxt = cur ^ 1;
    // issue prefetch for t+1 (consumed in P3 by waves 2..7)
    if (t < T_LEN-1 && tid >= 128) {
      const float* Ag = matA + (size_t)(tb+64)*4096;
      const float* Cg = matC + (size_t)(tb+64)*2048;
      { const int c = su;        pf0 = *(const float4*)&Ag[c*4]; }            // 0..383 all A
      { const int c = su + 384;  pf1 = *(const float4*)&Ag[c*4]; }            // 384..767 all A
      { const int c = su + 768;  pf2 = (c < 1024) ? *(const float4*)&Ag[c*4]
                                                  : *(const float4*)&Cg[(c-1024)*4]; }
      { const int c = su + 1152; pf3 = *(const float4*)&Cg[(c-1024)*4]; }     // all C
    }
    float areg = 0.f;
    if ((tid & 15) == 15) areg = as_[(size_t)tb*AD + (tid >> 4)];

    // ---- P1: CPaug = C @ covp_aug   (32 rows x 65)
    {
      const int i = tid >> 4, j0 = (tid & 15)*4;
      const bool do64 = ((tid & 15) == 15);
      const float* Crow = &Cm[cur][i*65];
      float4 acc = make_float4(0,0,0,0); float s64 = 0.f;
      #pragma unroll 8
      for (int k = 0; k < 64; ++k) {
        const float a = Crow[k];
        const float4 b4 = *(const float4*)&covp[k*68 + j0];
        acc.x += a*b4.x; acc.y += a*b4.y; acc.z += a*b4.z; acc.w += a*b4.w;
        if (do64) s64 += a * covp[k*68 + 64];
      }
      *(float4*)&CPm[i*68 + j0] = acc;
      if (do64) CPm[i*68 + 64] = s64 - areg;   // C meanp - a  (= -innov)
    }
    __syncthreads();
    // ---- P2: S = CP @ C^T + R   (32x32, 2 outputs/thread)
    {
      const int i = tid >> 4, j0 = (tid & 15)*2;
      const float* CProw = &CPm[i*68];
      const float* Cr0 = &Cm[cur][(j0+0)*65];
      const float* Cr1 = &Cm[cur][(j0+1)*65];
      float a0 = 0.f, a1 = 0.f;
      #pragma unroll 8
      for (int k = 0; k < 64; ++k) {
        const float cp = CProw[k];
        a0 += cp * Cr0[k];
        a1 += cp * Cr1[k];
      }
      Smat[i*36 + j0+0] = a0 + Rm[i*32 + j0+0];
      Smat[i*36 + j0+1] = a1 + Rm[i*32 + j0+1];
    }
    __syncthreads();
    // ---- P3: waves 0-1 Cholesky + solve; waves 2-7 stage t+1
    {
      const int wv = tid >> 6, lane = tid & 63;
      if (wv < 2) {
        float Lr[32];
        float invd = 0.f;   // lane k holds 1/L[k][k]; static select only
        if (lane < 32) {
          #pragma unroll
          for (int j = 0; j < 32; ++j) Lr[j] = Smat[lane*36 + j];
          #pragma unroll
          for (int k = 0; k < 32; ++k) {
            const float piv = __shfl(Lr[k], k);
            const float ir  = 1.0f / sqrtf(piv);
            const float lik = Lr[k] * ir;
            invd = (lane == k) ? ir : invd;
            #pragma unroll
            for (int j = k+1; j < 32; ++j) {
              const float ljk = __shfl(lik, j);
              Lr[j] -= lik * ljk;
            }
            Lr[k] = lik;
          }
        }
        // column-oriented forward solve; ALL 64 lanes stay active through
        // the shfl chain (shfl from inactive lane undefined — r2 bug).
        const int c = (wv == 0) ? lane : 64;
        {
          float s[32];
          #pragma unroll
          for (int i = 0; i < 32; ++i) s[i] = CPm[i*68 + c];
          #pragma unroll
          for (int k = 0; k < 32; ++k) {
            const float dk = __shfl(invd, k);
            const float y  = s[k] * dk;
            if (wv == 0 || lane == 0) Wm[k*68 + c] = y;
            #pragma unroll
            for (int i = k+1; i < 32; ++i) {
              const float lik = __shfl(Lr[k], i);
              s[i] -= lik * y;
            }
          }
        }
      } else if (t < T_LEN-1) {
        // stage t+1: A chunks 0..1023, C chunks 0..511 (float4 granularity)
        { const int c = su;        const int i = c>>4, j = (c&15)*4;
          At[nxt][(j+0)*68+i]=pf0.x; At[nxt][(j+1)*68+i]=pf0.y; At[nxt][(j+2)*68+i]=pf0.z; At[nxt][(j+3)*68+i]=pf0.w; }
        { const int c = su + 384;  const int i = c>>4, j = (c&15)*4;
          At[nxt][(j+0)*68+i]=pf1.x; At[nxt][(j+1)*68+i]=pf1.y; At[nxt][(j+2)*68+i]=pf1.z; At[nxt][(j+3)*68+i]=pf1.w; }
        { const int c = su + 768;
          if (c < 1024) { const int i = c>>4, j = (c&15)*4;
            At[nxt][(j+0)*68+i]=pf2.x; At[nxt][(j+1)*68+i]=pf2.y; At[nxt][(j+2)*68+i]=pf2.z; At[nxt][(j+3)*68+i]=pf2.w; }
          else { const int cc = c-1024; const int i = cc>>4, c0 = (cc&15)*4;
            Cm[nxt][i*65+c0]=pf2.x; Cm[nxt][i*65+c0+1]=pf2.y; Cm[nxt][i*65+c0+2]=pf2.z; Cm[nxt][i*65+c0+3]=pf2.w; } }
        { const int cc = su + 128; const int i = cc>>4, c0 = (cc&15)*4;
          Cm[nxt][i*65+c0]=pf3.x; Cm[nxt][i*65+c0+1]=pf3.y; Cm[nxt][i*65+c0+2]=pf3.z; Cm[nxt][i*65+c0+3]=pf3.w; }
      }
    }
    __syncthreads();
    // ---- P5: covt_aug = covp_aug - W^T W (in place); write covs, means
    {
      const int j = tid >> 3, c0 = (tid & 7)*8;
      const bool do64 = ((tid & 7) == 7);
      float4 a0 = make_float4(0,0,0,0), a1 = a0; float s64 = 0.f;
      #pragma unroll 4
      for (int k = 0; k < 32; ++k) {
        const float a = Wm[k*68 + j];
        const float4 b0 = *(const float4*)&Wm[k*68 + c0];
        const float4 b1 = *(const float4*)&Wm[k*68 + c0 + 4];
        a0.x += a*b0.x; a0.y += a*b0.y; a0.z += a*b0.z; a0.w += a*b0.w;
        a1.x += a*b1.x; a1.y += a*b1.y; a1.z += a*b1.z; a1.w += a*b1.w;
        if (do64) s64 += a * Wm[k*68 + 64];
      }
      float4 c4a = *(const float4*)&covp[j*68 + c0];
      float4 c4b = *(const float4*)&covp[j*68 + c0 + 4];
      c4a.x -= a0.x; c4a.y -= a0.y; c4a.z -= a0.z; c4a.w -= a0.w;
      c4b.x -= a1.x; c4b.y -= a1.y; c4b.z -= a1.z; c4b.w -= a1.w;
      *(float4*)&covp[j*68 + c0]     = c4a;
      *(float4*)&covp[j*68 + c0 + 4] = c4b;
      *(float4*)&covs[(size_t)tb*4096 + j*64 + c0]     = c4a;
      *(float4*)&covs[(size_t)tb*4096 + j*64 + c0 + 4] = c4b;
      if (do64) {
        const float mt = covp[j*68 + 64] - s64;   // mean_t
        covp[j*68 + 64] = mt;
        means[(size_t)tb*64 + j] = mt;
      }
    }
    __syncthreads();
    // ---- P6: tmpm = A @ covt_aug ; col64 = mean_next
    {
      const int i = tid >> 3, c0 = (tid & 7)*8;
      const bool do64 = ((tid & 7) == 7);
      const float* Atb = At[cur];
      float4 a0 = make_float4(0,0,0,0), a1 = a0; float s64 = 0.f;
      #pragma unroll 4
      for (int k = 0; k < 64; ++k) {
        const float a = Atb[k*68 + i];
        const float4 b0 = *(const float4*)&covp[k*68 + c0];
        const float4 b1 = *(const float4*)&covp[k*68 + c0 + 4];
        a0.x += a*b0.x; a0.y += a*b0.y; a0.z += a*b0.z; a0.w += a*b0.w;
        a1.x += a*b1.x; a1.y += a*b1.y; a1.z += a*b1.z; a1.w += a*b1.w;
        if (do64) s64 += a * covp[k*68 + 64];
      }
      *(float4*)&tmpm[i*68 + c0]     = a0;
      *(float4*)&tmpm[i*68 + c0 + 4] = a1;
      if (do64) {
        tmpm[i*68 + 64] = s64;
        nmeans[(size_t)tb*64 + i] = s64;
      }
    }
    __syncthreads();
    // ---- P7: covnext = tmpm @ A^T + Q -> covp ; carry mean_next
    {
      const int i = tid >> 3, j0 = (tid & 7)*8;
      const float* Atb  = At[cur];
      const float* trow = &tmpm[i*68];
      float4 a0 = make_float4(0,0,0,0), a1 = a0;
      #pragma unroll 4
      for (int k = 0; k < 64; ++k) {
        const float a = trow[k];
        const float4 b0 = *(const float4*)&Atb[k*68 + j0];
        const float4 b1 = *(const float4*)&Atb[k*68 + j0 + 4];
        a0.x += a*b0.x; a0.y += a*b0.y; a0.z += a*b0.z; a0.w += a*b0.w;
        a1.x += a*b1.x; a1.y += a*b1.y; a1.z += a*b1.z; a1.w += a*b1.w;
      }
      const float4 q0 = *(const float4*)&Ql[i*68 + j0];
      const float4 q1 = *(const float4*)&Ql[i*68 + j0 + 4];
      a0.x += q0.x; a0.y += q0.y; a0.z += q0.z; a0.w += q0.w;
      a1.x += q1.x; a1.y += q1.y; a1.z += q1.z; a1.w += q1.w;
      *(float4*)&covp[i*68 + j0]     = a0;
      *(float4*)&covp[i*68 + j0 + 4] = a1;
      if ((tid & 7) == 7) covp[i*68 + 64] = tmpm[i*68 + 64];
    }
    __syncthreads();
    // ---- P8: symmetrize (average) + write ncovs
    float4 m0, m1;
    {
      const int i = tid >> 3, j0 = (tid & 7)*8;
      const float4 o0 = *(const float4*)&covp[i*68 + j0];
      const float4 o1 = *(const float4*)&covp[i*68 + j0 + 4];
      m0.x = 0.5f*(o0.x + covp[(j0+0)*68 + i]);
      m0.y = 0.5f*(o0.y + covp[(j0+1)*68 + i]);
      m0.z = 0.5f*(o0.z + covp[(j0+2)*68 + i]);
      m0.w = 0.5f*(o0.w + covp[(j0+3)*68 + i]);
      m1.x = 0.5f*(o1.x + covp[(j0+4)*68 + i]);
      m1.y = 0.5f*(o1.y + covp[(j0+5)*68 + i]);
      m1.z = 0.5f*(o1.z + covp[(j0+6)*68 + i]);
      m1.w = 0.5f*(o1.w + covp[(j0+7)*68 + i]);
    }
    __syncthreads();
    {
      const int i = tid >> 3, j0 = (tid & 7)*8;
      *(float4*)&covp[i*68 + j0]     = m0;
      *(float4*)&covp[i*68 + j0 + 4] = m1;
      *(float4*)&ncovs[(size_t)tb*4096 + i*64 + j0]     = m0;
      *(float4*)&ncovs[(size_t)tb*4096 + i*64 + j0 + 4] = m1;
    }
    __syncthreads();
    cur = nxt;
  }
}

extern "C" void kernel_launch(void* const* d_in, const int* in_sizes, int n_in,
                              void* d_out, int out_size, void* d_ws, size_t ws_size,
                              hipStream_t stream) {
  const float* as_  = (const float*)d_in[0];
  const float* AK   = (const float*)d_in[1];
  const float* CK   = (const float*)d_in[2];
  const float* QL   = (const float*)d_in[3];
  const float* RL   = (const float*)d_in[4];
  const float* linW = (const float*)d_in[5];
  const float* linb = (const float*)d_in[6];
  const float* Wih0 = (const float*)d_in[7];
  const float* Whh0 = (const float*)d_in[8];
  const float* bih0 = (const float*)d_in[9];
  const float* bhh0 = (const float*)d_in[10];
  const float* Wih1 = (const float*)d_in[11];
  const float* Whh1 = (const float*)d_in[12];
  const float* bih1 = (const float*)d_in[13];
  const float* bhh1 = (const float*)d_in[14];
  float* out = (float*)d_out;
  float* ws  = (float*)d_ws;

  prep_kernel<<<856, 256, 0, stream>>>(Wih0, Whh0, bih0, bhh0,
                                       Wih1, Whh1, bih1, bhh1, QL, RL, ws);
  lstm_kernel<<<B_SZ, 512, 0, stream>>>(as_, ws, linW, linb, ws + WS_W);
  mix_kernel<<<(T_LEN*B_SZ)/16, 256, 0, stream>>>(ws + WS_W, AK, CK, out);
  kalman_kernel<<<B_SZ, 512, 0, stream>>>(as_, ws, out);
}

// Round 7
// 4888.534 us; speedup vs baseline: 2.5354x; 1.6250x over previous
//
#include <hip/hip_runtime.h>
#include <math.h>

// Problem dims
#define T_LEN 128
#define B_SZ  64
#define AD    32
#define ZD    64
#define KMIX  16
#define HID   128

// ---------------- workspace layout ----------------
// bf16 weights (ushort), packed [K/2][512][2] per matrix:
//   W0IH ushort ofs 0      (16384)
//   W0HH ushort ofs 16384  (65536)
//   W1IH ushort ofs 81920  (65536)
//   W1HH ushort ofs 147456 (65536)
// float region (offsets in floats):
#define WS_B0 106496
#define WS_B1 107008
#define WS_Q  107520
#define WS_R  111616
#define WS_W  112640

// ---------------- output layout (floats) ----------------
#define OUT_MEANS   0
#define OUT_COVS    524288
#define OUT_NMEANS  34078720
#define OUT_NCOVS   34603008
#define OUT_MATA    68157440
#define OUT_MATC    101711872

__device__ __forceinline__ float sigmoidf_(float x){ return 1.0f/(1.0f + expf(-x)); }

__device__ __forceinline__ unsigned short f2bf(float f){
  unsigned u = __float_as_uint(f);
  u += 0x7FFFu + ((u >> 16) & 1u);
  return (unsigned short)(u >> 16);
}

// ============ prep ============
__global__ __launch_bounds__(256) void prep_kernel(
    const float* __restrict__ Wih0, const float* __restrict__ Whh0,
    const float* __restrict__ bih0, const float* __restrict__ bhh0,
    const float* __restrict__ Wih1, const float* __restrict__ Whh1,
    const float* __restrict__ bih1, const float* __restrict__ bhh1,
    const float* __restrict__ QL,   const float* __restrict__ RL,
    float* __restrict__ ws)
{
  int idx = blockIdx.x*256 + threadIdx.x;
  unsigned short* w16 = (unsigned short*)ws;
  if (idx < 212992) {
    const float* src; int local, base, IN;
    if (idx < 16384)       { src = Wih0; local = idx;          base = 0;      IN = 32; }
    else if (idx < 81920)  { src = Whh0; local = idx - 16384;  base = 16384;  IN = 128; }
    else if (idx < 147456) { src = Wih1; local = idx - 81920;  base = 81920;  IN = 128; }
    else                   { src = Whh1; local = idx - 147456; base = 147456; IN = 128; }
    int pair = local >> 10, g = (local >> 1) & 511, lo = local & 1;
    int k = pair*2 + lo;
    w16[base + local] = f2bf(src[g*IN + k]);
  } else if (idx < 213504) {
    int g = idx - 212992; ws[WS_B0 + g] = bih0[g] + bhh0[g];
  } else if (idx < 214016) {
    int g = idx - 213504; ws[WS_B1 + g] = bih1[g] + bhh1[g];
  } else if (idx < 218112) {              // Q = QL QL^T + 1e-3 I
    int e = idx - 214016; int i = e >> 6, j = e & 63;
    float s = (i==j) ? 1e-3f : 0.f;
    for (int k = 0; k < 64; ++k) s += QL[i*64+k]*QL[j*64+k];
    ws[WS_Q + e] = s;
  } else if (idx < 219136) {              // R = RL RL^T + 1e-3 I
    int e = idx - 218112; int i = e >> 5, j = e & 31;
    float s = (i==j) ? 1e-3f : 0.f;
    for (int k = 0; k < 32; ++k) s += RL[i*32+k]*RL[j*32+k];
    ws[WS_R + e] = s;
  }
}

// ============ 2-layer LSTM + softmax head -> w[T][B][16] ============
__global__ __launch_bounds__(512) void lstm_kernel(
    const float* __restrict__ as_, const float* __restrict__ ws,
    const float* __restrict__ linW, const float* __restrict__ linb,
    float* __restrict__ wout)
{
  const int b = blockIdx.x, tid = threadIdx.x;
  const unsigned* W0ih = (const unsigned*)ws;        // [16][512]
  const unsigned* W0hh = W0ih + 16*512;              // [64][512]
  const unsigned* W1ih = W0hh + 64*512;              // [64][512]
  const unsigned* W1hh = W1ih + 64*512;              // [64][512]

  __shared__ float xs[32];
  __shared__ float h0[128];
  __shared__ float h1[128];
  __shared__ float gbuf[512];
  __shared__ float lg[16];

  float c0 = 0.f, c1 = 0.f;
  if (tid < 128) { h0[tid] = 0.f; h1[tid] = 0.f; }
  const float bias0 = ws[WS_B0 + tid];
  const float bias1 = ws[WS_B1 + tid];
  __syncthreads();

  for (int t = 0; t < T_LEN; ++t) {
    if (tid < 32) xs[tid] = as_[(t*B_SZ + b)*AD + tid];
    __syncthreads();
    { // layer 0
      float acc = bias0;
      #pragma unroll 4
      for (int kk = 0; kk < 16; ++kk) {
        const unsigned u = W0ih[kk*512 + tid];
        acc += __uint_as_float(u << 16) * xs[2*kk]
             + __uint_as_float(u & 0xFFFF0000u) * xs[2*kk+1];
      }
      #pragma unroll 8
      for (int kk = 0; kk < 64; ++kk) {
        const unsigned u = W0hh[kk*512 + tid];
        acc += __uint_as_float(u << 16) * h0[2*kk]
             + __uint_as_float(u & 0xFFFF0000u) * h0[2*kk+1];
      }
      gbuf[tid] = acc;
    }
    __syncthreads();
    if (tid < 128) {
      float ig = sigmoidf_(gbuf[tid]);
      float fg = sigmoidf_(gbuf[tid+128]);
      float gg = tanhf(gbuf[tid+256]);
      float og = sigmoidf_(gbuf[tid+384]);
      c0 = fg*c0 + ig*gg;
      h0[tid] = og * tanhf(c0);
    }
    __syncthreads();
    { // layer 1
      float acc = bias1;
      #pragma unroll 8
      for (int kk = 0; kk < 64; ++kk) {
        const unsigned u = W1ih[kk*512 + tid];
        acc += __uint_as_float(u << 16) * h0[2*kk]
             + __uint_as_float(u & 0xFFFF0000u) * h0[2*kk+1];
      }
      #pragma unroll 8
      for (int kk = 0; kk < 64; ++kk) {
        const unsigned u = W1hh[kk*512 + tid];
        acc += __uint_as_float(u << 16) * h1[2*kk]
             + __uint_as_float(u & 0xFFFF0000u) * h1[2*kk+1];
      }
      gbuf[tid] = acc;
    }
    __syncthreads();
    if (tid < 128) {
      float ig = sigmoidf_(gbuf[tid]);
      float fg = sigmoidf_(gbuf[tid+128]);
      float gg = tanhf(gbuf[tid+256]);
      float og = sigmoidf_(gbuf[tid+384]);
      c1 = fg*c1 + ig*gg;
      h1[tid] = og * tanhf(c1);
    }
    __syncthreads();
    if (tid < 16) {
      float acc = linb[tid];
      #pragma unroll 8
      for (int k = 0; k < 128; ++k) acc += linW[tid*128 + k] * h1[k];
      lg[tid] = acc;
    }
    __syncthreads();
    if (tid == 0) {
      float m = lg[0];
      #pragma unroll
      for (int k = 1; k < 16; ++k) m = fmaxf(m, lg[k]);
      float e[16]; float s = 0.f;
      #pragma unroll
      for (int k = 0; k < 16; ++k) { e[k] = expf(lg[k] - m); s += e[k]; }
      float inv = 1.f / s;
      #pragma unroll
      for (int k = 0; k < 16; ++k) wout[(t*B_SZ + b)*KMIX + k] = e[k]*inv;
    }
    __syncthreads();
  }
}

// ============ mix ============
__global__ __launch_bounds__(256) void mix_kernel(
    const float* __restrict__ w, const float* __restrict__ AK,
    const float* __restrict__ CK, float* __restrict__ out)
{
  float* matA = out + OUT_MATA;
  float* matC = out + OUT_MATC;
  const int tb0 = blockIdx.x * 16;
  const int tid = threadIdx.x;
  __shared__ float wl[16][16];
  { int lt = tid >> 4, k = tid & 15; wl[lt][k] = w[(tb0 + lt)*16 + k]; }
  __syncthreads();

  for (int e = tid; e < ZD*ZD; e += 256) {
    float v[16];
    #pragma unroll
    for (int u = 0; u < 16; ++u) v[u] = 0.f;
    #pragma unroll 4
    for (int k = 0; k < 16; ++k) {
      float a = AK[k*ZD*ZD + e];
      #pragma unroll
      for (int u = 0; u < 16; ++u) v[u] += wl[u][k] * a;
    }
    #pragma unroll
    for (int u = 0; u < 16; ++u) matA[(size_t)(tb0+u)*(ZD*ZD) + e] = v[u];
  }
  for (int e = tid; e < AD*ZD; e += 256) {
    float v[16];
    #pragma unroll
    for (int u = 0; u < 16; ++u) v[u] = 0.f;
    #pragma unroll 4
    for (int k = 0; k < 16; ++k) {
      float a = CK[k*AD*ZD + e];
      #pragma unroll
      for (int u = 0; u < 16; ++u) v[u] += wl[u][k] * a;
    }
    #pragma unroll
    for (int u = 0; u < 16; ++u) matC[(size_t)(tb0+u)*(AD*ZD) + e] = v[u];
  }
}

// ============ Kalman filter: one block (512 thr, 8 waves) per batch ============
// Register-pressure discipline (r5/r6 lesson): hipcc pins 512-thr kernels at
// 128 VGPR regardless of launch_bounds; Lr[32]+s[32] simultaneously live +
// 16 prefetch regs spilled -> 1.4 GB scratch writebacks/dispatch. Fix:
// P3 split by a barrier so Lr and s are never co-live, and staging loads
// global->LDS inside P3a (no cross-phase prefetch registers).
__global__ __launch_bounds__(512, 1) void kalman_kernel(
    const float* __restrict__ as_, const float* __restrict__ ws,
    float* __restrict__ out)
{
  const int b = blockIdx.x, tid = threadIdx.x;
  const float* Rm = ws + WS_R;
  const float* Qg = ws + WS_Q;
  const float* matA = out + OUT_MATA;
  const float* matC = out + OUT_MATC;
  float* means  = out + OUT_MEANS;
  float* covs   = out + OUT_COVS;
  float* nmeans = out + OUT_NMEANS;
  float* ncovs  = out + OUT_NCOVS;

  __shared__ __align__(16) float covp[64*68];   // aug: col 64 = meanp
  __shared__ __align__(16) float At[2][64*68];  // A^T, double-buffered
  __shared__ float Cm[2][32*65];                // C, stride 65
  __shared__ __align__(16) float CPm[32*68];    // [CP | Cmeanp - a]
  __shared__ __align__(16) float Wm[32*68];     // L^{-1} CPaug
  __shared__ float Smat[32*36];                 // S -> L (inv diag on diagonal)
  __shared__ __align__(16) float tmpm[64*68];   // A @ covt_aug
  __shared__ __align__(16) float Ql[64*68];     // Q staged

  // ---- init: covp = [I | 0], stage Q, stage t=0 A/C
  for (int e = tid; e < 64*64; e += 512) {
    const int i = e >> 6, j = e & 63;
    Ql[i*68 + j]   = Qg[e];
    covp[i*68 + j] = (i == j) ? 1.f : 0.f;
  }
  if (tid < 64) covp[tid*68 + 64] = 0.f;
  {
    const float* Ag = matA + (size_t)b*4096;
    const float* Cg = matC + (size_t)b*2048;
    for (int e = tid; e < 4096; e += 512) At[0][(e & 63)*68 + (e >> 6)] = Ag[e];
    for (int e = tid; e < 2048; e += 512) Cm[0][(e >> 6)*65 + (e & 63)] = Cg[e];
  }
  __syncthreads();

  const int su = tid - 128;         // staging thread index 0..383 (waves 2..7)

  int cur = 0;
  for (int t = 0; t < T_LEN; ++t) {
    const int tb = t*B_SZ + b;
    const int nxt = cur ^ 1;
    float areg = 0.f;
    if ((tid & 15) == 15) areg = as_[(size_t)tb*AD + (tid >> 4)];

    // ---- P1: CPaug = C @ covp_aug   (32 rows x 65)
    {
      const int i = tid >> 4, j0 = (tid & 15)*4;
      const bool do64 = ((tid & 15) == 15);
      const float* Crow = &Cm[cur][i*65];
      float4 acc = make_float4(0,0,0,0); float s64 = 0.f;
      #pragma unroll 8
      for (int k = 0; k < 64; ++k) {
        const float a = Crow[k];
        const float4 b4 = *(const float4*)&covp[k*68 + j0];
        acc.x += a*b4.x; acc.y += a*b4.y; acc.z += a*b4.z; acc.w += a*b4.w;
        if (do64) s64 += a * covp[k*68 + 64];
      }
      *(float4*)&CPm[i*68 + j0] = acc;
      if (do64) CPm[i*68 + 64] = s64 - areg;   // C meanp - a  (= -innov)
    }
    __syncthreads();
    // ---- P2: S = CP @ C^T + R   (32x32, 2 outputs/thread)
    {
      const int i = tid >> 4, j0 = (tid & 15)*2;
      const float* CProw = &CPm[i*68];
      const float* Cr0 = &Cm[cur][(j0+0)*65];
      const float* Cr1 = &Cm[cur][(j0+1)*65];
      float a0 = 0.f, a1 = 0.f;
      #pragma unroll 8
      for (int k = 0; k < 64; ++k) {
        const float cp = CProw[k];
        a0 += cp * Cr0[k];
        a1 += cp * Cr1[k];
      }
      Smat[i*36 + j0+0] = a0 + Rm[i*32 + j0+0];
      Smat[i*36 + j0+1] = a1 + Rm[i*32 + j0+1];
    }
    __syncthreads();
    // ---- P3a: wave 0 Cholesky -> L in Smat (inv diag on diagonal);
    //           waves 2-7 stage t+1 A/C global->LDS (latency hidden by chol)
    {
      const int wv = tid >> 6, lane = tid & 63;
      if (wv == 0) {
        if (lane < 32) {
          float Lr[32];
          float invd = 0.f;   // lane k holds 1/L[k][k]; static select only
                              // (runtime Lr[lane] = r3 scratch bug)
          #pragma unroll
          for (int j = 0; j < 32; ++j) Lr[j] = Smat[lane*36 + j];
          #pragma unroll
          for (int k = 0; k < 32; ++k) {
            const float piv = __shfl(Lr[k], k);
            const float ir  = 1.0f / sqrtf(piv);
            const float lik = Lr[k] * ir;
            invd = (lane == k) ? ir : invd;
            #pragma unroll
            for (int j = k+1; j < 32; ++j) {
              const float ljk = __shfl(lik, j);   // sources lanes k+1..31: active
              Lr[j] -= lik * ljk;
            }
            Lr[k] = lik;
          }
          // write back: strict lower triangle = L, diagonal = 1/L[k][k]
          #pragma unroll
          for (int j = 0; j < 32; ++j)
            if (j < lane) Smat[lane*36 + j] = Lr[j];
          Smat[lane*36 + lane] = invd;
        }
      } else if (wv >= 2 && t < T_LEN-1) {
        const float* Ag = matA + (size_t)(tb+64)*4096;
        const float* Cg = matC + (size_t)(tb+64)*2048;
        const float4 q0 = *(const float4*)&Ag[su*4];                 // A 0..383
        const float4 q1 = *(const float4*)&Ag[(su+384)*4];           // A 384..767
        const float4 q2 = (su < 256) ? *(const float4*)&Ag[(su+768)*4]
                                     : *(const float4*)&Cg[(su-256)*4];
        const float4 q3 = *(const float4*)&Cg[(su+128)*4];           // C 128..511
        { const int c = su;       const int i = c>>4, j = (c&15)*4;
          At[nxt][(j+0)*68+i]=q0.x; At[nxt][(j+1)*68+i]=q0.y; At[nxt][(j+2)*68+i]=q0.z; At[nxt][(j+3)*68+i]=q0.w; }
        { const int c = su + 384; const int i = c>>4, j = (c&15)*4;
          At[nxt][(j+0)*68+i]=q1.x; At[nxt][(j+1)*68+i]=q1.y; At[nxt][(j+2)*68+i]=q1.z; At[nxt][(j+3)*68+i]=q1.w; }
        if (su < 256) { const int c = su + 768; const int i = c>>4, j = (c&15)*4;
          At[nxt][(j+0)*68+i]=q2.x; At[nxt][(j+1)*68+i]=q2.y; At[nxt][(j+2)*68+i]=q2.z; At[nxt][(j+3)*68+i]=q2.w; }
        else { const int cc = su - 256; const int i = cc>>4, c0 = (cc&15)*4;
          Cm[nxt][i*65+c0]=q2.x; Cm[nxt][i*65+c0+1]=q2.y; Cm[nxt][i*65+c0+2]=q2.z; Cm[nxt][i*65+c0+3]=q2.w; }
        { const int cc = su + 128; const int i = cc>>4, c0 = (cc&15)*4;
          Cm[nxt][i*65+c0]=q3.x; Cm[nxt][i*65+c0+1]=q3.y; Cm[nxt][i*65+c0+2]=q3.z; Cm[nxt][i*65+c0+3]=q3.w; }
      }
    }
    __syncthreads();
    // ---- P3b: forward solve W = L^{-1} CPaug, one column per thread (65 cols).
    // L read from LDS at compile-time-static offsets (broadcast, hoistable);
    // only s[32] lives in registers here (Lr is dead -> no co-live arrays).
    if (tid < 65) {
      const int c = tid;
      float s[32];
      #pragma unroll
      for (int i = 0; i < 32; ++i) s[i] = CPm[i*68 + c];
      #pragma unroll
      for (int k = 0; k < 32; ++k) {
        const float y = s[k] * Smat[k*36 + k];     // diag holds 1/L[k][k]
        Wm[k*68 + c] = y;
        #pragma unroll
        for (int i = k+1; i < 32; ++i)
          s[i] -= Smat[i*36 + k] * y;
      }
    }
    __syncthreads();
    // ---- P5: covt_aug = covp_aug - W^T W (in place); write covs, means
    {
      const int j = tid >> 3, c0 = (tid & 7)*8;
      const bool do64 = ((tid & 7) == 7);
      float4 a0 = make_float4(0,0,0,0), a1 = a0; float s64 = 0.f;
      #pragma unroll 4
      for (int k = 0; k < 32; ++k) {
        const float a = Wm[k*68 + j];
        const float4 b0 = *(const float4*)&Wm[k*68 + c0];
        const float4 b1 = *(const float4*)&Wm[k*68 + c0 + 4];
        a0.x += a*b0.x; a0.y += a*b0.y; a0.z += a*b0.z; a0.w += a*b0.w;
        a1.x += a*b1.x; a1.y += a*b1.y; a1.z += a*b1.z; a1.w += a*b1.w;
        if (do64) s64 += a * Wm[k*68 + 64];
      }
      float4 c4a = *(const float4*)&covp[j*68 + c0];
      float4 c4b = *(const float4*)&covp[j*68 + c0 + 4];
      c4a.x -= a0.x; c4a.y -= a0.y; c4a.z -= a0.z; c4a.w -= a0.w;
      c4b.x -= a1.x; c4b.y -= a1.y; c4b.z -= a1.z; c4b.w -= a1.w;
      *(float4*)&covp[j*68 + c0]     = c4a;
      *(float4*)&covp[j*68 + c0 + 4] = c4b;
      *(float4*)&covs[(size_t)tb*4096 + j*64 + c0]     = c4a;
      *(float4*)&covs[(size_t)tb*4096 + j*64 + c0 + 4] = c4b;
      if (do64) {
        const float mt = covp[j*68 + 64] - s64;   // mean_t
        covp[j*68 + 64] = mt;
        means[(size_t)tb*64 + j] = mt;
      }
    }
    __syncthreads();
    // ---- P6: tmpm = A @ covt_aug ; col64 = mean_next
    {
      const int i = tid >> 3, c0 = (tid & 7)*8;
      const bool do64 = ((tid & 7) == 7);
      const float* Atb = At[cur];
      float4 a0 = make_float4(0,0,0,0), a1 = a0; float s64 = 0.f;
      #pragma unroll 4
      for (int k = 0; k < 64; ++k) {
        const float a = Atb[k*68 + i];
        const float4 b0 = *(const float4*)&covp[k*68 + c0];
        const float4 b1 = *(const float4*)&covp[k*68 + c0 + 4];
        a0.x += a*b0.x; a0.y += a*b0.y; a0.z += a*b0.z; a0.w += a*b0.w;
        a1.x += a*b1.x; a1.y += a*b1.y; a1.z += a*b1.z; a1.w += a*b1.w;
        if (do64) s64 += a * covp[k*68 + 64];
      }
      *(float4*)&tmpm[i*68 + c0]     = a0;
      *(float4*)&tmpm[i*68 + c0 + 4] = a1;
      if (do64) {
        tmpm[i*68 + 64] = s64;
        nmeans[(size_t)tb*64 + i] = s64;
      }
    }
    __syncthreads();
    // ---- P7: covnext = tmpm @ A^T + Q -> covp ; carry mean_next
    {
      const int i = tid >> 3, j0 = (tid & 7)*8;
      const float* Atb  = At[cur];
      const float* trow = &tmpm[i*68];
      float4 a0 = make_float4(0,0,0,0), a1 = a0;
      #pragma unroll 4
      for (int k = 0; k < 64; ++k) {
        const float a = trow[k];
        const float4 b0 = *(const float4*)&Atb[k*68 + j0];
        const float4 b1 = *(const float4*)&Atb[k*68 + j0 + 4];
        a0.x += a*b0.x; a0.y += a*b0.y; a0.z += a*b0.z; a0.w += a*b0.w;
        a1.x += a*b1.x; a1.y += a*b1.y; a1.z += a*b1.z; a1.w += a*b1.w;
      }
      const float4 q0 = *(const float4*)&Ql[i*68 + j0];
      const float4 q1 = *(const float4*)&Ql[i*68 + j0 + 4];
      a0.x += q0.x; a0.y += q0.y; a0.z += q0.z; a0.w += q0.w;
      a1.x += q1.x; a1.y += q1.y; a1.z += q1.z; a1.w += q1.w;
      *(float4*)&covp[i*68 + j0]     = a0;
      *(float4*)&covp[i*68 + j0 + 4] = a1;
      if ((tid & 7) == 7) covp[i*68 + 64] = tmpm[i*68 + 64];
    }
    __syncthreads();
    // ---- P8: symmetrize (average) + write ncovs
    float4 m0, m1;
    {
      const int i = tid >> 3, j0 = (tid & 7)*8;
      const float4 o0 = *(const float4*)&covp[i*68 + j0];
      const float4 o1 = *(const float4*)&covp[i*68 + j0 + 4];
      m0.x = 0.5f*(o0.x + covp[(j0+0)*68 + i]);
      m0.y = 0.5f*(o0.y + covp[(j0+1)*68 + i]);
      m0.z = 0.5f*(o0.z + covp[(j0+2)*68 + i]);
      m0.w = 0.5f*(o0.w + covp[(j0+3)*68 + i]);
      m1.x = 0.5f*(o1.x + covp[(j0+4)*68 + i]);
      m1.y = 0.5f*(o1.y + covp[(j0+5)*68 + i]);
      m1.z = 0.5f*(o1.z + covp[(j0+6)*68 + i]);
      m1.w = 0.5f*(o1.w + covp[(j0+7)*68 + i]);
    }
    __syncthreads();
    {
      const int i = tid >> 3, j0 = (tid & 7)*8;
      *(float4*)&covp[i*68 + j0]     = m0;
      *(float4*)&covp[i*68 + j0 + 4] = m1;
      *(float4*)&ncovs[(size_t)tb*4096 + i*64 + j0]     = m0;
      *(float4*)&ncovs[(size_t)tb*4096 + i*64 + j0 + 4] = m1;
    }
    __syncthreads();
    cur = nxt;
  }
}

extern "C" void kernel_launch(void* const* d_in, const int* in_sizes, int n_in,
                              void* d_out, int out_size, void* d_ws, size_t ws_size,
                              hipStream_t stream) {
  const float* as_  = (const float*)d_in[0];
  const float* AK   = (const float*)d_in[1];
  const float* CK   = (const float*)d_in[2];
  const float* QL   = (const float*)d_in[3];
  const float* RL   = (const float*)d_in[4];
  const float* linW = (const float*)d_in[5];
  const float* linb = (const float*)d_in[6];
  const float* Wih0 = (const float*)d_in[7];
  const float* Whh0 = (const float*)d_in[8];
  const float* bih0 = (const float*)d_in[9];
  const float* bhh0 = (const float*)d_in[10];
  const float* Wih1 = (const float*)d_in[11];
  const float* Whh1 = (const float*)d_in[12];
  const float* bih1 = (const float*)d_in[13];
  const float* bhh1 = (const float*)d_in[14];
  float* out = (float*)d_out;
  float* ws  = (float*)d_ws;

  prep_kernel<<<856, 256, 0, stream>>>(Wih0, Whh0, bih0, bhh0,
                                       Wih1, Whh1, bih1, bhh1, QL, RL, ws);
  lstm_kernel<<<B_SZ, 512, 0, stream>>>(as_, ws, linW, linb, ws + WS_W);
  mix_kernel<<<(T_LEN*B_SZ)/16, 256, 0, stream>>>(ws + WS_W, AK, CK, out);
  kalman_kernel<<<B_SZ, 512, 0, stream>>>(as_, ws, out);
}